// Round 5
// baseline (275.108 us; speedup 1.0000x reference)
//
#include <hip/hip_runtime.h>
#include <math.h>

// Problem constants
#define NVEC   65536      // B*H*W = 64*32*32
#define CDIM   64
#define KBOOK  1024
#define NTOT   4194304    // B*C*H*W
#define KSPLIT 4
#define KCHUNK (KBOOK / KSPLIT)   // 256

// d_out layout (float32): [quantized_z: NTOT][quantized_z_st: NTOT][indices: NVEC][perplexity: 1]
// workspace: u64 keys[NVEC] @0 ; float se[KBOOK] @524288 ; int hist[KBOOK] @528384

#define FOR64(M) \
  M(0) M(1) M(2) M(3) M(4) M(5) M(6) M(7) \
  M(8) M(9) M(10) M(11) M(12) M(13) M(14) M(15) \
  M(16) M(17) M(18) M(19) M(20) M(21) M(22) M(23) \
  M(24) M(25) M(26) M(27) M(28) M(29) M(30) M(31) \
  M(32) M(33) M(34) M(35) M(36) M(37) M(38) M(39) \
  M(40) M(41) M(42) M(43) M(44) M(45) M(46) M(47) \
  M(48) M(49) M(50) M(51) M(52) M(53) M(54) M(55) \
  M(56) M(57) M(58) M(59) M(60) M(61) M(62) M(63)

// init keys, zero hist, and compute se (||e_k||^2, numpy pairwise 8-acc, rn intrinsics)
__global__ void prep_kernel(const float* __restrict__ cb, unsigned long long* __restrict__ keys,
                            float* __restrict__ se, int* __restrict__ hist) {
    int t = blockIdx.x * 256 + threadIdx.x;   // grid 256 -> t in [0, NVEC)
    keys[t] = 0xFFFFFFFFFFFFFFFFull;
    if (t < KBOOK) {
        hist[t] = 0;
        const float* row = cb + t * CDIM;
        float r[8];
#pragma unroll
        for (int j = 0; j < 8; ++j) r[j] = __fmul_rn(row[j], row[j]);
#pragma unroll
        for (int i = 8; i < 64; i += 8)
#pragma unroll
            for (int j = 0; j < 8; ++j) r[j] = __fadd_rn(r[j], __fmul_rn(row[i + j], row[i + j]));
        se[t] = __fadd_rn(__fadd_rn(__fadd_rn(r[0], r[1]), __fadd_rn(r[2], r[3])),
                          __fadd_rn(__fadd_rn(r[4], r[5]), __fadd_rn(r[6], r[7])));
    }
}

// Bit-exact dists = fl(fl(sx+se_k) - a_nk), a = ascending-c fmaf chain on zx=2z.
// z held as 64 NAMED scalars (no array -> nothing for SROA to miss), each pinned
// once via opaque asm so the k-loop cannot rematerialize the global loads.
// K split 4 ways over blockIdx.y; chunks merged via ordered-key atomicMin
// (value-then-index lexicographic == numpy first-min argmin).
__launch_bounds__(128, 4)
__global__ void argmin_kernel(const float* __restrict__ z, const float* __restrict__ cb,
                              const float* __restrict__ se,
                              unsigned long long* __restrict__ keys) {
    const int t = threadIdx.x;
    const int n = blockIdx.x * 128 + t;
    const int k0 = blockIdx.y * KCHUNK;
    const int b = n >> 10, hw = n & 1023;
    const float* zb = z + (size_t)b * (CDIM * 1024) + hw;

    float r0_, r1_, r2_, r3_, r4_, r5_, r6_, r7_;
    // zx = 2*z (exact); sx = numpy pairwise 8-acc sum of fl(z^2)
#define LOADZ(c)                                                        \
    float z_##c; {                                                      \
        float zc = zb[(c) * 1024];                                      \
        z_##c = zc + zc;                                                \
        float q = __fmul_rn(zc, zc);                                    \
        if ((c) < 8) { if ((c)==0) r0_=q; else if ((c)==1) r1_=q; else if ((c)==2) r2_=q; \
                       else if ((c)==3) r3_=q; else if ((c)==4) r4_=q; else if ((c)==5) r5_=q; \
                       else if ((c)==6) r6_=q; else r7_=q; }            \
        else { switch ((c) & 7) {                                       \
            case 0: r0_ = __fadd_rn(r0_, q); break;                     \
            case 1: r1_ = __fadd_rn(r1_, q); break;                     \
            case 2: r2_ = __fadd_rn(r2_, q); break;                     \
            case 3: r3_ = __fadd_rn(r3_, q); break;                     \
            case 4: r4_ = __fadd_rn(r4_, q); break;                     \
            case 5: r5_ = __fadd_rn(r5_, q); break;                     \
            case 6: r6_ = __fadd_rn(r6_, q); break;                     \
            default: r7_ = __fadd_rn(r7_, q); break; } }                \
    }
    FOR64(LOADZ)
#undef LOADZ
    const float sx = __fadd_rn(__fadd_rn(__fadd_rn(r0_, r1_), __fadd_rn(r2_, r3_)),
                               __fadd_rn(__fadd_rn(r4_, r5_), __fadd_rn(r6_, r7_)));

    // Pin each scalar once: opaque SSA def -> no remat of the z loads in the k-loop.
#define PINZ(c) asm volatile("" : "+v"(z_##c));
    FOR64(PINZ)
#undef PINZ

    float best = 3.4e38f;
    int bi = k0;

    for (int k = k0; k < k0 + KCHUNK; k += 4) {
        const float* __restrict__ row = cb + (size_t)k * CDIM;  // wave-uniform -> s_load
        float a0 = 0.f, a1 = 0.f, a2 = 0.f, a3 = 0.f;           // 4 indep fmaf chains
#define FMASTEP(c)                              \
        a0 = fmaf(z_##c, row[(c)], a0);         \
        a1 = fmaf(z_##c, row[(c) + 64], a1);    \
        a2 = fmaf(z_##c, row[(c) + 128], a2);   \
        a3 = fmaf(z_##c, row[(c) + 192], a3);
        FOR64(FMASTEP)
#undef FMASTEP
        const float d0 = __fsub_rn(__fadd_rn(sx, se[k]), a0);
        const float d1 = __fsub_rn(__fadd_rn(sx, se[k + 1]), a1);
        const float d2 = __fsub_rn(__fadd_rn(sx, se[k + 2]), a2);
        const float d3 = __fsub_rn(__fadd_rn(sx, se[k + 3]), a3);
        if (d0 < best) { best = d0; bi = k; }        // strict <, ascending k: first-min
        if (d1 < best) { best = d1; bi = k + 1; }
        if (d2 < best) { best = d2; bi = k + 2; }
        if (d3 < best) { best = d3; bi = k + 3; }
    }

    // ordered-float key: monotonic uint32 over all floats; idx in low bits
    unsigned int ob = __float_as_uint(best);
    ob = (ob & 0x80000000u) ? ~ob : (ob | 0x80000000u);
    atomicMin(&keys[n], ((unsigned long long)ob << 32) | (unsigned int)bi);
}

// quantized_z = cb[idx]; quantized_z_st = fl(z + fl(q - z)); float4-vectorized
__global__ void scatter_kernel(const float* __restrict__ z, const float* __restrict__ cb,
                               const unsigned long long* __restrict__ keys,
                               float* __restrict__ out) {
    const int o = (blockIdx.x * 256 + threadIdx.x) * 4;    // [0, NTOT), step 4
    const int b = o >> 16, c = (o >> 10) & 63, hw = o & 1023;
    const int n = (b << 10) | hw;
    float q[4];
#pragma unroll
    for (int j = 0; j < 4; ++j) {
        const int k = (int)(keys[n + j] & 0xFFFFFFFFu);
        q[j] = cb[k * CDIM + c];
    }
    const float4 zv = *(const float4*)(z + o);
    *(float4*)(out + o) = make_float4(q[0], q[1], q[2], q[3]);
    float4 st;
    st.x = __fadd_rn(zv.x, __fsub_rn(q[0], zv.x));
    st.y = __fadd_rn(zv.y, __fsub_rn(q[1], zv.y));
    st.z = __fadd_rn(zv.z, __fsub_rn(q[2], zv.z));
    st.w = __fadd_rn(zv.w, __fsub_rn(q[3], zv.w));
    *(float4*)(out + NTOT + o) = st;
}

// histogram + indices-as-float
__global__ void hist_kernel(const unsigned long long* __restrict__ keys, int* __restrict__ hist,
                            float* __restrict__ outIdxF) {
    __shared__ int lh[KBOOK];
    for (int i = threadIdx.x; i < KBOOK; i += 256) lh[i] = 0;
    __syncthreads();
    const int n = blockIdx.x * 256 + threadIdx.x;          // grid = 256 blocks
    const int k = (int)(keys[n] & 0xFFFFFFFFu);
    outIdxF[n] = (float)k;
    atomicAdd(&lh[k], 1);
    __syncthreads();
    for (int i = threadIdx.x; i < KBOOK; i += 256)
        if (lh[i]) atomicAdd(&hist[i], lh[i]);
}

__global__ void perp_kernel(const int* __restrict__ hist, float* __restrict__ out) {
    __shared__ double partial[16];
    const int t = threadIdx.x;  // 1024 threads
    const int c = hist[t];
    double term = 0.0;
    if (c > 0) { double p = (double)c / (double)NVEC; term = p * log(p); }
    for (int off = 32; off > 0; off >>= 1) term += __shfl_down(term, off);
    if ((t & 63) == 0) partial[t >> 6] = term;
    __syncthreads();
    if (t == 0) {
        double s = 0.0;
        for (int i = 0; i < 16; ++i) s += partial[i];
        out[2 * NTOT + NVEC] = (float)exp(-s);
    }
}

extern "C" void kernel_launch(void* const* d_in, const int* in_sizes, int n_in,
                              void* d_out, int out_size, void* d_ws, size_t ws_size,
                              hipStream_t stream) {
    const float* z  = (const float*)d_in[0];   // [64,64,32,32]
    const float* cb = (const float*)d_in[1];   // [1024,64]
    float* out = (float*)d_out;

    char* ws = (char*)d_ws;
    unsigned long long* keys = (unsigned long long*)(ws + 0);
    float* se   = (float*)(ws + 524288);
    int*   hist = (int*)(ws + 528384);

    prep_kernel<<<256, 256, 0, stream>>>(cb, keys, se, hist);
    dim3 ag(NVEC / 128, KSPLIT);
    argmin_kernel<<<ag, 128, 0, stream>>>(z, cb, se, keys);
    scatter_kernel<<<NTOT / 1024, 256, 0, stream>>>(z, cb, keys, out);
    hist_kernel<<<NVEC / 256, 256, 0, stream>>>(keys, hist, out + 2 * NTOT);
    perp_kernel<<<1, 1024, 0, stream>>>(hist, out);
}

// Round 6
// 268.385 us; speedup vs baseline: 1.0251x; 1.0251x over previous
//
#include <hip/hip_runtime.h>
#include <math.h>

// Problem constants
#define NVEC   65536      // B*H*W = 64*32*32
#define CDIM   64
#define KBOOK  1024
#define NTOT   4194304    // B*C*H*W
#define KSPLIT 4
#define KCHUNK (KBOOK / KSPLIT)   // 256

// d_out layout (float32): [quantized_z: NTOT][quantized_z_st: NTOT][indices: NVEC][perplexity: 1]
// workspace: u64 keys[NVEC] @0 ; float se[KBOOK] @524288 ; int hist[KBOOK] @528384

#define FOR64(M) \
  M(0) M(1) M(2) M(3) M(4) M(5) M(6) M(7) \
  M(8) M(9) M(10) M(11) M(12) M(13) M(14) M(15) \
  M(16) M(17) M(18) M(19) M(20) M(21) M(22) M(23) \
  M(24) M(25) M(26) M(27) M(28) M(29) M(30) M(31) \
  M(32) M(33) M(34) M(35) M(36) M(37) M(38) M(39) \
  M(40) M(41) M(42) M(43) M(44) M(45) M(46) M(47) \
  M(48) M(49) M(50) M(51) M(52) M(53) M(54) M(55) \
  M(56) M(57) M(58) M(59) M(60) M(61) M(62) M(63)

// init keys, zero hist, and compute se (||e_k||^2, numpy pairwise 8-acc, rn intrinsics)
__global__ void prep_kernel(const float* __restrict__ cb, unsigned long long* __restrict__ keys,
                            float* __restrict__ se, int* __restrict__ hist) {
    int t = blockIdx.x * 256 + threadIdx.x;   // grid 256 -> t in [0, NVEC)
    keys[t] = 0xFFFFFFFFFFFFFFFFull;
    if (t < KBOOK) {
        hist[t] = 0;
        const float* row = cb + t * CDIM;
        float r[8];
#pragma unroll
        for (int j = 0; j < 8; ++j) r[j] = __fmul_rn(row[j], row[j]);
#pragma unroll
        for (int i = 8; i < 64; i += 8)
#pragma unroll
            for (int j = 0; j < 8; ++j) r[j] = __fadd_rn(r[j], __fmul_rn(row[i + j], row[i + j]));
        se[t] = __fadd_rn(__fadd_rn(__fadd_rn(r[0], r[1]), __fadd_rn(r[2], r[3])),
                          __fadd_rn(__fadd_rn(r[4], r[5]), __fadd_rn(r[6], r[7])));
    }
}

// Bit-exact dists = fl(fl(sx+se_k) - a_nk), a = ascending-c fmaf chain on zx=2z.
// z held as 64 NAMED scalars, pinned via opaque asm.
// amdgpu_waves_per_eu(4,4): occupancy MAX = 4 waves/EU -> the pressure-min
// scheduler has no incentive to spill z to AGPRs (round-5 failure: VGPR=40,
// v_accvgpr_read per fmaf doubled VALU work). Budget 128 VGPR, need ~80.
// k-unroll reduced 4->2: small body, low peak pressure; latency hidden by TLP
// (2048 blocks x 2 waves = 4 waves/SIMD co-resident).
__launch_bounds__(128)
__attribute__((amdgpu_waves_per_eu(4, 4)))
__global__ void argmin_kernel(const float* __restrict__ z, const float* __restrict__ cb,
                              const float* __restrict__ se,
                              unsigned long long* __restrict__ keys) {
    const int t = threadIdx.x;
    const int n = blockIdx.x * 128 + t;
    const int k0 = blockIdx.y * KCHUNK;
    const int b = n >> 10, hw = n & 1023;
    const float* zb = z + (size_t)b * (CDIM * 1024) + hw;

    float r0_, r1_, r2_, r3_, r4_, r5_, r6_, r7_;
    // zx = 2*z (exact); sx = numpy pairwise 8-acc sum of fl(z^2)
#define LOADZ(c)                                                        \
    float z_##c; {                                                      \
        float zc = zb[(c) * 1024];                                      \
        z_##c = zc + zc;                                                \
        float q = __fmul_rn(zc, zc);                                    \
        if ((c) < 8) { if ((c)==0) r0_=q; else if ((c)==1) r1_=q; else if ((c)==2) r2_=q; \
                       else if ((c)==3) r3_=q; else if ((c)==4) r4_=q; else if ((c)==5) r5_=q; \
                       else if ((c)==6) r6_=q; else r7_=q; }            \
        else { switch ((c) & 7) {                                       \
            case 0: r0_ = __fadd_rn(r0_, q); break;                     \
            case 1: r1_ = __fadd_rn(r1_, q); break;                     \
            case 2: r2_ = __fadd_rn(r2_, q); break;                     \
            case 3: r3_ = __fadd_rn(r3_, q); break;                     \
            case 4: r4_ = __fadd_rn(r4_, q); break;                     \
            case 5: r5_ = __fadd_rn(r5_, q); break;                     \
            case 6: r6_ = __fadd_rn(r6_, q); break;                     \
            default: r7_ = __fadd_rn(r7_, q); break; } }                \
    }
    FOR64(LOADZ)
#undef LOADZ
    const float sx = __fadd_rn(__fadd_rn(__fadd_rn(r0_, r1_), __fadd_rn(r2_, r3_)),
                               __fadd_rn(__fadd_rn(r4_, r5_), __fadd_rn(r6_, r7_)));

    // Opaque SSA def: blocks remat of the z loads inside the k-loop.
#define PINZ(c) asm volatile("" : "+v"(z_##c));
    FOR64(PINZ)
#undef PINZ

    float best = 3.4e38f;
    int bi = k0;

    for (int k = k0; k < k0 + KCHUNK; k += 2) {
        const float* __restrict__ row = cb + (size_t)k * CDIM;  // wave-uniform -> s_load
        float a0 = 0.f, a1 = 0.f;                               // 2 indep fmaf chains
#define FMASTEP(c)                              \
        a0 = fmaf(z_##c, row[(c)], a0);         \
        a1 = fmaf(z_##c, row[(c) + 64], a1);
        FOR64(FMASTEP)
#undef FMASTEP
        const float d0 = __fsub_rn(__fadd_rn(sx, se[k]), a0);
        const float d1 = __fsub_rn(__fadd_rn(sx, se[k + 1]), a1);
        if (d0 < best) { best = d0; bi = k; }        // strict <, ascending k: first-min
        if (d1 < best) { best = d1; bi = k + 1; }
    }

    // ordered-float key: monotonic uint32 over all floats; idx in low bits
    unsigned int ob = __float_as_uint(best);
    ob = (ob & 0x80000000u) ? ~ob : (ob | 0x80000000u);
    atomicMin(&keys[n], ((unsigned long long)ob << 32) | (unsigned int)bi);
}

// quantized_z = cb[idx]; quantized_z_st = fl(z + fl(q - z)); float4-vectorized
__global__ void scatter_kernel(const float* __restrict__ z, const float* __restrict__ cb,
                               const unsigned long long* __restrict__ keys,
                               float* __restrict__ out) {
    const int o = (blockIdx.x * 256 + threadIdx.x) * 4;    // [0, NTOT), step 4
    const int b = o >> 16, c = (o >> 10) & 63, hw = o & 1023;
    const int n = (b << 10) | hw;
    float q[4];
#pragma unroll
    for (int j = 0; j < 4; ++j) {
        const int k = (int)(keys[n + j] & 0xFFFFFFFFu);
        q[j] = cb[k * CDIM + c];
    }
    const float4 zv = *(const float4*)(z + o);
    *(float4*)(out + o) = make_float4(q[0], q[1], q[2], q[3]);
    float4 st;
    st.x = __fadd_rn(zv.x, __fsub_rn(q[0], zv.x));
    st.y = __fadd_rn(zv.y, __fsub_rn(q[1], zv.y));
    st.z = __fadd_rn(zv.z, __fsub_rn(q[2], zv.z));
    st.w = __fadd_rn(zv.w, __fsub_rn(q[3], zv.w));
    *(float4*)(out + NTOT + o) = st;
}

// histogram + indices-as-float
__global__ void hist_kernel(const unsigned long long* __restrict__ keys, int* __restrict__ hist,
                            float* __restrict__ outIdxF) {
    __shared__ int lh[KBOOK];
    for (int i = threadIdx.x; i < KBOOK; i += 256) lh[i] = 0;
    __syncthreads();
    const int n = blockIdx.x * 256 + threadIdx.x;          // grid = 256 blocks
    const int k = (int)(keys[n] & 0xFFFFFFFFu);
    outIdxF[n] = (float)k;
    atomicAdd(&lh[k], 1);
    __syncthreads();
    for (int i = threadIdx.x; i < KBOOK; i += 256)
        if (lh[i]) atomicAdd(&hist[i], lh[i]);
}

__global__ void perp_kernel(const int* __restrict__ hist, float* __restrict__ out) {
    __shared__ double partial[16];
    const int t = threadIdx.x;  // 1024 threads
    const int c = hist[t];
    double term = 0.0;
    if (c > 0) { double p = (double)c / (double)NVEC; term = p * log(p); }
    for (int off = 32; off > 0; off >>= 1) term += __shfl_down(term, off);
    if ((t & 63) == 0) partial[t >> 6] = term;
    __syncthreads();
    if (t == 0) {
        double s = 0.0;
        for (int i = 0; i < 16; ++i) s += partial[i];
        out[2 * NTOT + NVEC] = (float)exp(-s);
    }
}

extern "C" void kernel_launch(void* const* d_in, const int* in_sizes, int n_in,
                              void* d_out, int out_size, void* d_ws, size_t ws_size,
                              hipStream_t stream) {
    const float* z  = (const float*)d_in[0];   // [64,64,32,32]
    const float* cb = (const float*)d_in[1];   // [1024,64]
    float* out = (float*)d_out;

    char* ws = (char*)d_ws;
    unsigned long long* keys = (unsigned long long*)(ws + 0);
    float* se   = (float*)(ws + 524288);
    int*   hist = (int*)(ws + 528384);

    prep_kernel<<<256, 256, 0, stream>>>(cb, keys, se, hist);
    dim3 ag(NVEC / 128, KSPLIT);
    argmin_kernel<<<ag, 128, 0, stream>>>(z, cb, se, keys);
    scatter_kernel<<<NTOT / 1024, 256, 0, stream>>>(z, cb, keys, out);
    hist_kernel<<<NVEC / 256, 256, 0, stream>>>(keys, hist, out + 2 * NTOT);
    perp_kernel<<<1, 1024, 0, stream>>>(hist, out);
}